// Round 1
// baseline (196.014 us; speedup 1.0000x reference)
//
#include <hip/hip_runtime.h>
#include <hip/hip_bf16.h>

#define EMBED 1024
#define HEADS 16
#define HDIM  64
#define BATCH 4
#define SEQ   1024

typedef __attribute__((ext_vector_type(8))) short  short8;
typedef __attribute__((ext_vector_type(4))) short  short4v;
typedef __attribute__((ext_vector_type(4))) float  float4v;

// f32 -> bf16 (RNE)
static __device__ __forceinline__ short f2b(float f) {
  unsigned u = __builtin_bit_cast(unsigned, f);
  unsigned r = (u + 0x7FFFu + ((u >> 16) & 1u)) >> 16;
  return (short)(unsigned short)r;
}

static __device__ __forceinline__ short8 cvt8(const float* p) {
  float4v a = *(const float4v*)p;
  float4v b = *(const float4v*)(p + 4);
  short8 r;
  r[0]=f2b(a[0]); r[1]=f2b(a[1]); r[2]=f2b(a[2]); r[3]=f2b(a[3]);
  r[4]=f2b(b[0]); r[5]=f2b(b[1]); r[6]=f2b(b[2]); r[7]=f2b(b[3]);
  return r;
}

// ---------------------------------------------------------------------------
// Kernel 1: per-head projections q/k/v.  1 wave per (16 rows, head, tensor).
// out[s][o] = sum_d in[s][h*64+d] * W[o][d]   (A = in rows, B = W^T)
// qp/kp layout: [n*H+h][s][64] bf16.   vpT layout: [n*H+h][d][s] bf16.
// ---------------------------------------------------------------------------
__global__ __launch_bounds__(64) void k_proj(
    const float* __restrict__ values, const float* __restrict__ keys,
    const float* __restrict__ query,
    const float* __restrict__ Wv, const float* __restrict__ Wq,
    const float* __restrict__ Wk,
    short* __restrict__ qp, short* __restrict__ kp, short* __restrict__ vpT) {
  const int r0 = blockIdx.x * 16;     // row over B*S
  const int h  = blockIdx.y;
  const int z  = blockIdx.z;          // 0=q, 1=k, 2=v
  const float* in_; const float* W;
  if (z == 0)      { in_ = query;  W = Wq; }
  else if (z == 1) { in_ = keys;   W = Wk; }
  else             { in_ = values; W = Wv; }
  const int l = threadIdx.x, lr = l & 15, g = l >> 4;
  const int n = r0 >> 10, s0 = r0 & 1023;
  const int nh = n * HEADS + h;

  float4v acc[4];
  for (int nt = 0; nt < 4; ++nt) acc[nt] = (float4v){0.f, 0.f, 0.f, 0.f};

  for (int kb = 0; kb < 2; ++kb) {
    // A frag: lane holds A[row=lr][k=g*8+j] of the 16x32 slice
    short8 af = cvt8(in_ + (size_t)(r0 + lr) * EMBED + h * HDIM + kb * 32 + g * 8);
    for (int nt = 0; nt < 4; ++nt) {
      // B frag: lane holds B[k=g*8+j][col=lr] = W[nt*16+lr][kb*32+g*8+j]
      short8 bf = cvt8(W + (size_t)(nt * 16 + lr) * HDIM + kb * 32 + g * 8);
      acc[nt] = __builtin_amdgcn_mfma_f32_16x16x32_bf16(af, bf, acc[nt], 0, 0, 0);
    }
  }
  // D layout: row = g*4+i, col = lr
  if (z == 2) {
    for (int nt = 0; nt < 4; ++nt) {
      short4v r;
      r[0]=f2b(acc[nt][0]); r[1]=f2b(acc[nt][1]);
      r[2]=f2b(acc[nt][2]); r[3]=f2b(acc[nt][3]);
      *(short4v*)(vpT + (size_t)(nh * HDIM + nt * 16 + lr) * SEQ + s0 + g * 4) = r;
    }
  } else {
    short* outp = (z == 0) ? qp : kp;
    for (int nt = 0; nt < 4; ++nt)
      for (int i = 0; i < 4; ++i)
        outp[(size_t)(nh * SEQ + s0 + g * 4 + i) * HDIM + nt * 16 + lr] = f2b(acc[nt][i]);
  }
}

// ---------------------------------------------------------------------------
// Kernel 2: compress mask (B,1,S,S) int32 -> bitmask (bit=1 means keep)
// ---------------------------------------------------------------------------
__global__ __launch_bounds__(256) void k_maskbits(const int* __restrict__ mask,
                                                  unsigned* __restrict__ mbits) {
  int tid = blockIdx.x * 256 + threadIdx.x;
  int v = mask[tid];
  unsigned long long bal = __ballot(v != 0);
  int l = threadIdx.x & 63;
  if ((l & 31) == 0) mbits[tid >> 5] = (unsigned)(bal >> (l & 32));
}

// ---------------------------------------------------------------------------
// Kernel 3: Wu -> bf16
// ---------------------------------------------------------------------------
__global__ __launch_bounds__(256) void k_wcvt(const float* __restrict__ Wu,
                                              short* __restrict__ wub) {
  int i4 = (blockIdx.x * 256 + threadIdx.x) * 4;
  float4v v = *(const float4v*)(Wu + i4);
  short4v r; r[0]=f2b(v[0]); r[1]=f2b(v[1]); r[2]=f2b(v[2]); r[3]=f2b(v[3]);
  *(short4v*)(wub + i4) = r;
}

// ---------------------------------------------------------------------------
// Kernel 4: flash attention.  1 wave per (n, h, 16 q-rows). 32-key tiles.
// Softmax in log2 domain (scale = log2(e)/32 folded into logits).
// ---------------------------------------------------------------------------
__global__ __launch_bounds__(64) void k_attn(
    const short* __restrict__ qp, const short* __restrict__ kp,
    const short* __restrict__ vpT, const unsigned* __restrict__ mbits,
    short* __restrict__ ao) {
  const int q0 = blockIdx.x * 16;
  const int h = blockIdx.y, n = blockIdx.z;
  const int l = threadIdx.x, lr = l & 15, g = l >> 4;
  const int nh = n * HEADS + h;
  const short* qb = qp  + (size_t)nh * SEQ * HDIM;
  const short* kbp = kp + (size_t)nh * SEQ * HDIM;
  const short* vb = vpT + (size_t)nh * HDIM * SEQ;

  // Q fragments for d in [0,32) and [32,64)
  short8 qf0 = *(const short8*)(qb + (q0 + lr) * HDIM + g * 8);
  short8 qf1 = *(const short8*)(qb + (q0 + lr) * HDIM + 32 + g * 8);

  float4v accd[4];
  for (int dt = 0; dt < 4; ++dt) accd[dt] = (float4v){0.f, 0.f, 0.f, 0.f};
  float m_i[4], l_i[4];
  for (int i = 0; i < 4; ++i) { m_i[i] = -3.0e18f; l_i[i] = 0.f; }

  __shared__ __align__(16) short plds[16 * 32];

  const float SCL = 0.045084220028f; // log2(e) / 32

  for (int kt = 0; kt < SEQ; kt += 32) {
    // ---- QK^T: scores 16q x 32k in two 16x16 accs
    float4v sa0 = (float4v){0.f,0.f,0.f,0.f}, sa1 = (float4v){0.f,0.f,0.f,0.f};
    {
      short8 b0 = *(const short8*)(kbp + (size_t)(kt + lr) * HDIM + g * 8);
      short8 b1 = *(const short8*)(kbp + (size_t)(kt + 16 + lr) * HDIM + g * 8);
      sa0 = __builtin_amdgcn_mfma_f32_16x16x32_bf16(qf0, b0, sa0, 0, 0, 0);
      sa1 = __builtin_amdgcn_mfma_f32_16x16x32_bf16(qf0, b1, sa1, 0, 0, 0);
      b0 = *(const short8*)(kbp + (size_t)(kt + lr) * HDIM + 32 + g * 8);
      b1 = *(const short8*)(kbp + (size_t)(kt + 16 + lr) * HDIM + 32 + g * 8);
      sa0 = __builtin_amdgcn_mfma_f32_16x16x32_bf16(qf1, b0, sa0, 0, 0, 0);
      sa1 = __builtin_amdgcn_mfma_f32_16x16x32_bf16(qf1, b1, sa1, 0, 0, 0);
    }
    // ---- mask + scale (D layout: lane holds rows g*4+i, col lr / 16+lr)
    const int wi = kt >> 5;
    float sv0[4], sv1[4], tm[4];
    for (int i = 0; i < 4; ++i) {
      unsigned mw = mbits[(size_t)(n * SEQ + q0 + g * 4 + i) * 32 + wi];
      float s0 = sa0[i] * SCL;
      float s1 = sa1[i] * SCL;
      if (!((mw >> lr) & 1u))        s0 = -3.0e18f;
      if (!((mw >> (16 + lr)) & 1u)) s1 = -3.0e18f;
      sv0[i] = s0; sv1[i] = s1;
      tm[i] = fmaxf(s0, s1);
    }
    // ---- row max over the 16-lane group (cols)
    for (int off = 1; off < 16; off <<= 1)
      for (int i = 0; i < 4; ++i)
        tm[i] = fmaxf(tm[i], __shfl_xor(tm[i], off, 64));
    // ---- online softmax update
    float p0[4], p1[4], rs[4], sca[4];
    for (int i = 0; i < 4; ++i) {
      float mn = fmaxf(m_i[i], tm[i]);
      float sc = exp2f(m_i[i] - mn);
      m_i[i] = mn;
      p0[i] = exp2f(sv0[i] - mn);
      p1[i] = exp2f(sv1[i] - mn);
      rs[i] = p0[i] + p1[i];
      sca[i] = sc;
      l_i[i] *= sc;
    }
    for (int off = 1; off < 16; off <<= 1)
      for (int i = 0; i < 4; ++i)
        rs[i] += __shfl_xor(rs[i], off, 64);
    for (int i = 0; i < 4; ++i) l_i[i] += rs[i];
    for (int dt = 0; dt < 4; ++dt)
      for (int i = 0; i < 4; ++i)
        accd[dt][i] *= sca[i];
    // ---- P -> LDS (D layout) -> read back as A frag
    __syncthreads();
    for (int i = 0; i < 4; ++i) {
      plds[(g * 4 + i) * 32 + lr]      = f2b(p0[i]);
      plds[(g * 4 + i) * 32 + 16 + lr] = f2b(p1[i]);
    }
    __syncthreads();
    short8 pf = *(const short8*)(plds + lr * 32 + g * 8);
    // ---- PV: acc[16q x 64d] += P(16x32) * V(32x64), V from vpT [d][s]
    for (int dt = 0; dt < 4; ++dt) {
      short8 vf = *(const short8*)(vb + (size_t)(dt * 16 + lr) * SEQ + kt + g * 8);
      accd[dt] = __builtin_amdgcn_mfma_f32_16x16x32_bf16(pf, vf, accd[dt], 0, 0, 0);
    }
  }
  // ---- epilogue: divide by l, store bf16 to ao [n][s][h*64+d]
  for (int dt = 0; dt < 4; ++dt)
    for (int i = 0; i < 4; ++i) {
      float o = accd[dt][i] / l_i[i];
      int row = q0 + g * 4 + i;
      ao[(size_t)(n * SEQ + row) * EMBED + h * HDIM + dt * 16 + lr] = f2b(o);
    }
}

// ---------------------------------------------------------------------------
// Kernel 5: out = ao @ Wu^T + bu.  64x64 tile, 4 waves, LDS-staged bf16 tiles
// with stride-40 (bf16) padding -> even 8-words/bank for all b128 frag reads.
// ---------------------------------------------------------------------------
__global__ __launch_bounds__(256) void k_gemm(
    const short* __restrict__ ao, const short* __restrict__ wub,
    const float* __restrict__ bu, float* __restrict__ out) {
  const int r0 = blockIdx.x * 64, c0 = blockIdx.y * 64;
  const int t = threadIdx.x;
  const int w = t >> 6, l = t & 63, lr = l & 15, g = l >> 4;
  __shared__ __align__(16) short albuf[64 * 40];
  __shared__ __align__(16) short blbuf[64 * 40];
  float4v acc[4];
  for (int nt = 0; nt < 4; ++nt) acc[nt] = (float4v){0.f, 0.f, 0.f, 0.f};
  const int lrow = t >> 2, lcb = (t & 3) * 8;
  for (int kbk = 0; kbk < EMBED; kbk += 32) {
    __syncthreads();
    *(short8*)(albuf + lrow * 40 + lcb) =
        *(const short8*)(ao + (size_t)(r0 + lrow) * EMBED + kbk + lcb);
    *(short8*)(blbuf + lrow * 40 + lcb) =
        *(const short8*)(wub + (size_t)(c0 + lrow) * EMBED + kbk + lcb);
    __syncthreads();
    short8 af = *(const short8*)(albuf + (16 * w + lr) * 40 + g * 8);
    for (int nt = 0; nt < 4; ++nt) {
      short8 bf = *(const short8*)(blbuf + (nt * 16 + lr) * 40 + g * 8);
      acc[nt] = __builtin_amdgcn_mfma_f32_16x16x32_bf16(af, bf, acc[nt], 0, 0, 0);
    }
  }
  for (int nt = 0; nt < 4; ++nt)
    for (int i = 0; i < 4; ++i) {
      int row = r0 + 16 * w + g * 4 + i;
      int col = c0 + nt * 16 + lr;
      out[(size_t)row * EMBED + col] = acc[nt][i] + bu[col];
    }
}

// ---------------------------------------------------------------------------
extern "C" void kernel_launch(void* const* d_in, const int* in_sizes, int n_in,
                              void* d_out, int out_size, void* d_ws, size_t ws_size,
                              hipStream_t stream) {
  const float* values = (const float*)d_in[0];
  const float* keys   = (const float*)d_in[1];
  const float* query  = (const float*)d_in[2];
  const int*   mask   = (const int*)d_in[3];
  const float* Wv     = (const float*)d_in[4];
  const float* Wq     = (const float*)d_in[5];
  const float* Wk     = (const float*)d_in[6];
  const float* Wu     = (const float*)d_in[7];
  const float* bu     = (const float*)d_in[8];
  float* out = (float*)d_out;

  char* ws = (char*)d_ws;
  short* qp  = (short*)ws;                        // 8 MB  (4M bf16)
  short* kp  = qp + (1u << 22);                   // 8 MB
  short* vpT = kp + (1u << 22);                   // 8 MB (transposed V)
  short* ao  = vpT + (1u << 22);                  // 8 MB
  unsigned* mbits = (unsigned*)(ws + (32u << 20));        // 512 KB
  short* wub = (short*)(ws + (32u << 20) + (512u << 10)); // 2 MB
  // total ws use: 34.5 MB

  k_proj<<<dim3(256, 16, 3), 64, 0, stream>>>(values, keys, query, Wv, Wq, Wk,
                                              qp, kp, vpT);
  k_maskbits<<<dim3(16384), 256, 0, stream>>>(mask, mbits);
  k_wcvt<<<dim3(1024), 256, 0, stream>>>(Wu, wub);
  k_attn<<<dim3(64, 16, 4), 64, 0, stream>>>(qp, kp, vpT, mbits, ao);
  k_gemm<<<dim3(64, 16), 256, 0, stream>>>(ao, wub, bu, out);
}